// Round 2
// baseline (825.805 us; speedup 1.0000x reference)
//
#include <hip/hip_runtime.h>
#include <math.h>

#define L 8
#define H 1024
#define NH 16
#define KVH 4
#define HD 64
#define INTER 2816
#define VOCAB 32000
#define CTX 2048
#define EPS 1e-5f
#define NCHUNK 32          // CTX / 64
#define PART_STRIDE 68     // m, l, o[64], pad

__device__ inline float wave_reduce_sum(float v) {
    #pragma unroll
    for (int off = 32; off > 0; off >>= 1)
        v += __shfl_xor(v, off, 64);
    return v;
}

__device__ inline float wave_reduce_max(float v) {
    #pragma unroll
    for (int off = 32; off > 0; off >>= 1)
        v = fmaxf(v, __shfl_xor(v, off, 64));
    return v;
}

// h = embed[input_ids[0]]; also zero the attention chunk-counters
__global__ void embed_kernel(const float* __restrict__ embed, const int* __restrict__ ids,
                             float* __restrict__ h, int* __restrict__ cnt) {
    int t = threadIdx.x;
    const float4* e4 = (const float4*)(embed + (size_t)ids[0] * H);
    ((float4*)h)[t] = e4[t];
    if (t < 16) cnt[t] = 0;
}

// Fused rmsnorm + qkv matvec. Each block recomputes x = rms(h)*w into LDS,
// then 4 waves each produce one output row (1536 rows total).
__global__ __launch_bounds__(256) void qkv_rms_kernel(
    const float* __restrict__ qw, const float* __restrict__ kw,
    const float* __restrict__ vw, const float* __restrict__ h,
    const float* __restrict__ lnw,
    float* __restrict__ q, float* __restrict__ k, float* __restrict__ v) {
    __shared__ float xs[H];
    __shared__ float red4[4];
    int t = threadIdx.x, wave = t >> 6, lane = t & 63;
    float4 hv = ((const float4*)h)[t];
    float ss = hv.x*hv.x + hv.y*hv.y + hv.z*hv.z + hv.w*hv.w;
    ss = wave_reduce_sum(ss);
    if (lane == 0) red4[wave] = ss;
    __syncthreads();
    float rs = rsqrtf((red4[0]+red4[1]+red4[2]+red4[3]) * (1.f/(float)H) + EPS);
    float4 wv = ((const float4*)lnw)[t];
    float4 xv;
    xv.x = hv.x*rs*wv.x; xv.y = hv.y*rs*wv.y;
    xv.z = hv.z*rs*wv.z; xv.w = hv.w*rs*wv.w;
    ((float4*)xs)[t] = xv;
    __syncthreads();
    int row = blockIdx.x * 4 + wave;
    const float* W; float* out; int r;
    if (row < H)            { W = qw; out = q; r = row; }
    else if (row < H + 256) { W = kw; out = k; r = row - H; }
    else                    { W = vw; out = v; r = row - H - 256; }
    const float4* W4 = (const float4*)(W + (size_t)r * H);
    const float4* x4 = (const float4*)xs;
    float acc = 0.f;
    #pragma unroll
    for (int i = lane; i < H/4; i += 64) {
        float4 a = W4[i], b = x4[i];
        acc += a.x*b.x + a.y*b.y + a.z*b.z + a.w*b.w;
    }
    acc = wave_reduce_sum(acc);
    if (lane == 0) out[r] = acc;
}

// ---- flash-decode split attention, with fused RoPE and fused last-block combine ----
// grid (NH, NCHUNK); each block handles 64 positions for one q-head.
// q/kx arrive UN-rotated; rope is applied in-block (q for all, k only at pg==pos).
__global__ __launch_bounds__(256) void attn_kernel(
    const float* __restrict__ q, const float* __restrict__ kx,
    const float* __restrict__ vx, const float* __restrict__ kcache,
    const float* __restrict__ vcache, const float* __restrict__ cos_c,
    const float* __restrict__ sin_c, const int* __restrict__ pos_p,
    float* __restrict__ part, int* __restrict__ cnt, float* __restrict__ ao) {
    int hh = blockIdx.x, c = blockIdx.y;
    int pos = pos_p[0];
    int p0 = c * 64;
    if (p0 > pos) return;                      // fully-masked chunk
    int t = threadIdx.x;
    __shared__ float Kt[64 * 65];              // transposed [d][p], stride 65
    __shared__ float Vt[64 * 64];              // [p][d]
    __shared__ float qs[64];
    __shared__ float e_s[64];
    __shared__ float red[256];
    __shared__ int lastFlag;
    int kvh = hh >> 2;                         // n_rep = 4
    const float* K = kcache + (size_t)kvh * CTX * HD;
    const float* V = vcache + (size_t)kvh * CTX * HD;
    const float* cr = cos_c + (size_t)pos * HD;
    const float* sr = sin_c + (size_t)pos * HD;
    if (t < 64) {                              // q with RoPE applied in-register
        float a = q[hh * HD + t];
        float b = q[hh * HD + (t ^ 32)];
        float sgn = (t < 32) ? -1.f : 1.f;     // rotate_half: (-x2, x1)
        qs[t] = a * cr[t] + sgn * b * sr[t];
    }
    // cooperative tile load: 1024 float4 per tile, 4 per thread, coalesced
    #pragma unroll
    for (int j = t; j < 1024; j += 256) {
        int p = j >> 4, dq = j & 15;
        int pg = p0 + p;
        float4 kv4, vv4;
        if (pg > pos) {
            kv4 = make_float4(0.f, 0.f, 0.f, 0.f); vv4 = kv4;
        } else if (pg == pos) {                // new k/v with RoPE on k
            float4 a  = *(const float4*)(kx + kvh * HD + dq * 4);
            float4 b  = *(const float4*)(kx + kvh * HD + (dq ^ 8) * 4);
            float4 c4 = *(const float4*)(cr + dq * 4);
            float4 s4 = *(const float4*)(sr + dq * 4);
            float sgn = (dq < 8) ? -1.f : 1.f;
            kv4.x = a.x*c4.x + sgn*b.x*s4.x;
            kv4.y = a.y*c4.y + sgn*b.y*s4.y;
            kv4.z = a.z*c4.z + sgn*b.z*s4.z;
            kv4.w = a.w*c4.w + sgn*b.w*s4.w;
            vv4 = *(const float4*)(vx + kvh * HD + dq * 4);
        } else {
            kv4 = *(const float4*)(K + (size_t)pg * HD + dq * 4);
            vv4 = *(const float4*)(V + (size_t)pg * HD + dq * 4);
        }
        Kt[(4 * dq + 0) * 65 + p] = kv4.x;
        Kt[(4 * dq + 1) * 65 + p] = kv4.y;
        Kt[(4 * dq + 2) * 65 + p] = kv4.z;
        Kt[(4 * dq + 3) * 65 + p] = kv4.w;
        *(float4*)(Vt + p * 64 + dq * 4) = vv4;
    }
    __syncthreads();
    // wave 0: scores + chunk-local softmax stats
    if (t < 64) {
        int pg = p0 + t;
        float acc = 0.f;
        #pragma unroll 8
        for (int i = 0; i < 64; ++i)
            acc += qs[i] * Kt[i * 65 + t];
        float s = (pg > pos) ? -INFINITY : acc * 0.125f;
        float m = wave_reduce_max(s);
        float e = (pg > pos) ? 0.f : expf(s - m);
        float lsum = wave_reduce_sum(e);
        e_s[t] = e;
        if (t == 0) {
            float* pb = part + (size_t)(hh * NCHUNK + c) * PART_STRIDE;
            pb[0] = m; pb[1] = lsum;
        }
    }
    __syncthreads();
    // all 256 threads: partial output o_c[d] = sum_p e[p] * V[p][d]
    int g = t >> 6, d = t & 63;
    float acc = 0.f;
    #pragma unroll
    for (int pp = 0; pp < 16; ++pp) {
        int p = g * 16 + pp;
        acc += e_s[p] * Vt[p * 64 + d];
    }
    red[t] = acc;
    __syncthreads();
    if (t < 64) {
        float o = red[t] + red[64 + t] + red[128 + t] + red[192 + t];
        part[(size_t)(hh * NCHUNK + c) * PART_STRIDE + 2 + t] = o;
    }
    // ---- last-block-done combine (flash-decode split-K semaphore) ----
    __syncthreads();                           // all partial writes issued+drained (vmcnt before barrier)
    int nc = (pos >> 6) + 1;                   // number of active chunks
    if (t == 0) {
        __threadfence();                       // release: partials visible device-wide
        lastFlag = (atomicAdd(&cnt[hh], 1) == nc - 1);
    }
    __syncthreads();
    if (!lastFlag) return;
    __threadfence();                           // acquire: invalidate stale cache lines
    if (t < 64) {
        const volatile float* pa = part + (size_t)hh * NCHUNK * PART_STRIDE;
        float M = -INFINITY;
        for (int cc = 0; cc < nc; ++cc)
            M = fmaxf(M, pa[(size_t)cc * PART_STRIDE]);
        float Lsum = 0.f, oacc = 0.f;
        for (int cc = 0; cc < nc; ++cc) {
            const volatile float* pb = pa + (size_t)cc * PART_STRIDE;
            float w = expf(pb[0] - M);
            Lsum += w * pb[1];
            oacc += w * pb[2 + t];
        }
        ao[hh * HD + t] = oacc / Lsum;
    }
    if (t == 0) cnt[hh] = 0;                   // reset for next layer
}

// generic matvec, wave per row, optional residual; NC = compile-time ncols
template<int NC>
__global__ __launch_bounds__(256) void matvec_kernel(
    const float* __restrict__ W, const float* __restrict__ x,
    const float* __restrict__ res, float* __restrict__ y, int nrows) {
    int wave = threadIdx.x >> 6, lane = threadIdx.x & 63;
    int row = blockIdx.x * 4 + wave;
    if (row >= nrows) return;
    const float4* W4 = (const float4*)(W + (size_t)row * NC);
    const float4* x4 = (const float4*)x;
    float acc = 0.f;
    #pragma unroll
    for (int i = lane; i < NC/4; i += 64) {
        float4 a = W4[i], b = x4[i];
        acc += a.x*b.x + a.y*b.y + a.z*b.z + a.w*b.w;
    }
    acc = wave_reduce_sum(acc);
    if (lane == 0) y[row] = (res ? res[row] : 0.f) + acc;
}

// Fused rmsnorm + gate/up: t[i] = silu(gate_w[i,:].x) * (up_w[i,:].x)
__global__ __launch_bounds__(256) void gateup_rms_kernel(
    const float* __restrict__ gw, const float* __restrict__ uw,
    const float* __restrict__ h2, const float* __restrict__ lnw,
    float* __restrict__ t_out) {
    __shared__ float xs[H];
    __shared__ float red4[4];
    int t = threadIdx.x, wave = t >> 6, lane = t & 63;
    float4 hv = ((const float4*)h2)[t];
    float ss = hv.x*hv.x + hv.y*hv.y + hv.z*hv.z + hv.w*hv.w;
    ss = wave_reduce_sum(ss);
    if (lane == 0) red4[wave] = ss;
    __syncthreads();
    float rs = rsqrtf((red4[0]+red4[1]+red4[2]+red4[3]) * (1.f/(float)H) + EPS);
    float4 wv = ((const float4*)lnw)[t];
    float4 xv;
    xv.x = hv.x*rs*wv.x; xv.y = hv.y*rs*wv.y;
    xv.z = hv.z*rs*wv.z; xv.w = hv.w*rs*wv.w;
    ((float4*)xs)[t] = xv;
    __syncthreads();
    int row = blockIdx.x * 4 + wave;
    const float4* g4 = (const float4*)(gw + (size_t)row * H);
    const float4* u4 = (const float4*)(uw + (size_t)row * H);
    const float4* x4 = (const float4*)xs;
    float ag = 0.f, au = 0.f;
    #pragma unroll
    for (int i = lane; i < H/4; i += 64) {
        float4 b = x4[i];
        float4 a = g4[i];
        ag += a.x*b.x + a.y*b.y + a.z*b.z + a.w*b.w;
        float4 c = u4[i];
        au += c.x*b.x + c.y*b.y + c.z*b.z + c.w*b.w;
    }
    ag = wave_reduce_sum(ag);
    au = wave_reduce_sum(au);
    if (lane == 0) {
        float sg = ag / (1.f + expf(-ag));     // silu
        t_out[row] = sg * au;
    }
}

// Fused final rmsnorm + lm_head matvec + per-block argmax (packed u64, no logits buffer)
__global__ __launch_bounds__(256) void lmhead_kernel(
    const float* __restrict__ W, const float* __restrict__ h,
    const float* __restrict__ lnw, unsigned long long* __restrict__ blockmax) {
    __shared__ float xs[H];
    __shared__ float red4[4];
    __shared__ float rv[4];
    __shared__ int   ri[4];
    int t = threadIdx.x, wave = t >> 6, lane = t & 63;
    float4 hv = ((const float4*)h)[t];
    float ss = hv.x*hv.x + hv.y*hv.y + hv.z*hv.z + hv.w*hv.w;
    ss = wave_reduce_sum(ss);
    if (lane == 0) red4[wave] = ss;
    __syncthreads();
    float rs = rsqrtf((red4[0]+red4[1]+red4[2]+red4[3]) * (1.f/(float)H) + EPS);
    float4 wv = ((const float4*)lnw)[t];
    float4 xv;
    xv.x = hv.x*rs*wv.x; xv.y = hv.y*rs*wv.y;
    xv.z = hv.z*rs*wv.z; xv.w = hv.w*rs*wv.w;
    ((float4*)xs)[t] = xv;
    __syncthreads();
    int row = blockIdx.x * 4 + wave;
    const float4* W4 = (const float4*)(W + (size_t)row * H);
    const float4* x4 = (const float4*)xs;
    float acc = 0.f;
    #pragma unroll
    for (int i = lane; i < H/4; i += 64) {
        float4 a = W4[i], b = x4[i];
        acc += a.x*b.x + a.y*b.y + a.z*b.z + a.w*b.w;
    }
    acc = wave_reduce_sum(acc);
    if (lane == 0) { rv[wave] = acc; ri[wave] = row; }
    __syncthreads();
    if (t == 0) {
        float bm = rv[0]; int bi = ri[0];
        #pragma unroll
        for (int i = 1; i < 4; ++i)
            if (rv[i] > bm) { bm = rv[i]; bi = ri[i]; }   // rows ascending: '>' keeps first max
        unsigned int ub = __float_as_uint(bm);
        unsigned int enc = (ub & 0x80000000u) ? ~ub : (ub | 0x80000000u); // order-preserving
        blockmax[blockIdx.x] =
            ((unsigned long long)enc << 32) | (unsigned long long)(~(unsigned int)bi);
    }
}

// single block: max-reduce 8000 packed (value,~idx) words, decode to out
__global__ void lmfinal_kernel(const unsigned long long* __restrict__ bm,
                               float* __restrict__ out) {
    __shared__ unsigned long long sred[256];
    int t = threadIdx.x;
    unsigned long long v = 0ULL;
    for (int i = t; i < VOCAB / 4; i += 256) {
        unsigned long long u = bm[i];
        if (u > v) v = u;
    }
    sred[t] = v;
    __syncthreads();
    for (int off = 128; off > 0; off >>= 1) {
        if (t < off && sred[t + off] > sred[t]) sred[t] = sred[t + off];
        __syncthreads();
    }
    if (t == 0) {
        unsigned long long r = sred[0];
        unsigned int enc = (unsigned int)(r >> 32);
        unsigned int bits = (enc & 0x80000000u) ? (enc & 0x7FFFFFFFu) : ~enc;
        int idx = (int)(~(unsigned int)(r & 0xFFFFFFFFu));
        out[0] = (float)idx;
        out[1] = __uint_as_float(bits);
    }
}

extern "C" void kernel_launch(void* const* d_in, const int* in_sizes, int n_in,
                              void* d_out, int out_size, void* d_ws, size_t ws_size,
                              hipStream_t stream) {
    const float* embed   = (const float*)d_in[0];
    const float* q_w     = (const float*)d_in[1];
    const float* k_w     = (const float*)d_in[2];
    const float* v_w     = (const float*)d_in[3];
    const float* o_w     = (const float*)d_in[4];
    const float* gate_w  = (const float*)d_in[5];
    const float* up_w    = (const float*)d_in[6];
    const float* down_w  = (const float*)d_in[7];
    const float* ln1_w   = (const float*)d_in[8];
    const float* ln2_w   = (const float*)d_in[9];
    const float* norm_w  = (const float*)d_in[10];
    const float* lm_head = (const float*)d_in[11];
    const float* kv_cache= (const float*)d_in[12];
    const float* cos_c   = (const float*)d_in[13];
    const float* sin_c   = (const float*)d_in[14];
    const int* input_ids    = (const int*)d_in[17];
    const int* position_ids = (const int*)d_in[18];

    float* ws = (float*)d_ws;
    float* h      = ws;            // 1024
    float* h2     = ws + 1024;     // 1024
    float* qb     = ws + 2048;     // 1024
    float* kb     = ws + 3072;     // 256
    float* vb     = ws + 3328;     // 256
    float* aob    = ws + 3584;     // 1024
    float* tb     = ws + 4608;     // 2816
    float* part   = ws + 7424;     // NH*NCHUNK*PART_STRIDE = 34816 → ends 42240
    int*   cnt    = (int*)(ws + 42240);                       // 16 attn semaphores
    unsigned long long* blockmax = (unsigned long long*)(ws + 42256); // 8000 u64

    embed_kernel<<<1, 256, 0, stream>>>(embed, input_ids, h, cnt);
    for (int l = 0; l < L; ++l) {
        qkv_rms_kernel<<<(H + 2 * KVH * HD) / 4, 256, 0, stream>>>(
            q_w + (size_t)l * H * H, k_w + (size_t)l * KVH * HD * H,
            v_w + (size_t)l * KVH * HD * H, h, ln1_w + (size_t)l * H,
            qb, kb, vb);
        attn_kernel<<<dim3(NH, NCHUNK), 256, 0, stream>>>(
            qb, kb, vb,
            kv_cache + (size_t)l * KVH * CTX * HD,
            kv_cache + (size_t)(L + l) * KVH * CTX * HD,
            cos_c, sin_c, position_ids, part, cnt, aob);
        matvec_kernel<H><<<H / 4, 256, 0, stream>>>(
            o_w + (size_t)l * H * H, aob, h, h2, H);
        gateup_rms_kernel<<<INTER / 4, 256, 0, stream>>>(
            gate_w + (size_t)l * INTER * H, up_w + (size_t)l * INTER * H,
            h2, ln2_w + (size_t)l * H, tb);
        matvec_kernel<INTER><<<H / 4, 256, 0, stream>>>(
            down_w + (size_t)l * H * INTER, tb, h2, h, H);
    }
    lmhead_kernel<<<VOCAB / 4, 256, 0, stream>>>(lm_head, h, norm_w, blockmax);
    lmfinal_kernel<<<1, 256, 0, stream>>>(blockmax, (float*)d_out);
}